// Round 9
// baseline (281.101 us; speedup 1.0000x reference)
//
#include <hip/hip_runtime.h>
#include <math.h>

#define HH 384
#define WW 384
#define NIMG 272
#define IMG_STRIDE (HH * WW)
#define BWD 128                      // band width (px)
#define XB 3                         // bands per image row
#define SEG 32                       // output rows per unit
#define YS (HH / SEG)                // 12 vertical segments
#define UPI (XB * YS)                // 36 units per image
#define UNITS (NIMG * UPI)           // 9792
#define GPB 8                        // 32-lane groups per 256-thread block
#define NBLOCKS (UNITS / GPB)        // 1224, % 8 == 0
#define NXCD 8

typedef float f4_t __attribute__((ext_vector_type(4)));

__device__ __forceinline__ float max3f(float a, float b, float c) {
    return fmaxf(fmaxf(a, b), c);    // -> v_max3_f32
}
__device__ __forceinline__ float fast_sigmoid(float v) {
    return __fdividef(1.0f, 1.0f + __expf(-v));
}

// Round-9: continuous-issue rolling register pipeline (the LayerNorm shape:
// the only structure class measured at 82-86% HBM on this box, never tried
// here). All four prior structures are one-shot burst->compute->exit and tie
// at 2.4-2.6 TB/s with every pipe idle. Here a 32-lane group owns a 128x32
// segment and walks 34 rows with a ping-pong A/B 4-row batch double-buffer:
// batch m+1's loads are in flight during batch m's compute, every consume,
// for the whole wave lifetime. Peak ~100 live VGPR < 128 cap -> regalloc has
// no pressure reason to re-cluster the batches (r2's failure: 140+ demand).
// No LDS, no barriers; halo via width-32 __shfl; edge cols via one
// exec-masked load (lanes 0/31) per row. 1224 blocks (CP launch rate and
// 1-wave-block residency quantization out of the picture).
__global__ __launch_bounds__(256, 4) void
heatmap_peaks_roll(const float* __restrict__ in, float* __restrict__ out) {
    const float NEG = -INFINITY;
    const f4_t NEG4 = {NEG, NEG, NEG, NEG};

    int tid = (int)threadIdx.x;
    int f4c = tid & 31;              // f4-column within band
    int grp = tid >> 5;              // 0..7: unit within block
    int bid = (int)blockIdx.x;
    int swz = (bid % NXCD) * (NBLOCKS / NXCD) + bid / NXCD;  // bijective
    int u   = swz * GPB + grp;
    int img = u / UPI;
    int rem = u % UPI;
    int ys  = rem % YS;              // consecutive groups -> same band,
    int xb  = rem / YS;              //   adjacent segments: shared halo in L2
    int x0  = xb * BWD;
    int y0  = ys * SEG;

    const float* ib = in + (size_t)img * IMG_STRIDE;
    int xc = x0 + 4 * f4c;
    const float* cb = ib + xc;

    const bool eL = (f4c == 0), eR = (f4c == 31);
    const bool has_l = (x0 > 0), has_r = (x0 + BWD < WW);
    int ex = eR ? (has_r ? x0 + BWD : WW - 1) : (has_l ? x0 - 1 : 0);
    const float* eb = ib + ex;       // clamped, always-valid edge column
    const bool edge = (eL && has_l) || (eR && has_r);

    // load rows y0+ry0 .. y0+ry0+3 (row-clamped) + exec-masked edge scalar
    auto LD4 = [&](int ry0, f4_t* Bv, float* Ev) {
#pragma unroll
        for (int r2 = 0; r2 < 4; ++r2) {
            int gy = y0 + ry0 + r2;
            gy = gy < 0 ? 0 : (gy > HH - 1 ? HH - 1 : gy);
            Bv[r2] = *(const f4_t*)(cb + (size_t)gy * WW);
            if (edge) Ev[r2] = eb[(size_t)gy * WW];
        }
    };
    // horizontal 3-max; halo from neighbor lane (width-32 shfl) or edge scalar
    auto HM = [&](f4_t b, float e) -> f4_t {
        float lw = __shfl_up(b.w, 1, 32);
        float rx = __shfl_down(b.x, 1, 32);
        float L = eL ? (has_l ? e : NEG) : lw;
        float R = eR ? (has_r ? e : NEG) : rx;
        f4_t h;
        h.x = max3f(L,   b.x, b.y);
        h.y = max3f(b.x, b.y, b.z);
        h.z = max3f(b.y, b.z, b.w);
        h.w = max3f(b.z, b.w, R);
        return h;
    };

    float* ob = out + (size_t)img * IMG_STRIDE + (size_t)y0 * WW + xc;
    auto EMIT = [&](int oy, f4_t v, f4_t a, f4_t b, f4_t c) {
        f4_t o; float m, p;
        m = max3f(a.x, b.x, c.x); p = fast_sigmoid(v.x);
        o.x = (m == v.x && p > 0.05f) ? p : 0.0f;
        m = max3f(a.y, b.y, c.y); p = fast_sigmoid(v.y);
        o.y = (m == v.y && p > 0.05f) ? p : 0.0f;
        m = max3f(a.z, b.z, c.z); p = fast_sigmoid(v.z);
        o.z = (m == v.z && p > 0.05f) ? p : 0.0f;
        m = max3f(a.w, b.w, c.w); p = fast_sigmoid(v.w);
        o.w = (m == v.w && p > 0.05f) ? p : 0.0f;
        __builtin_nontemporal_store(o, (f4_t*)(ob + (size_t)oy * WW));
    };

    f4_t A[4], B[4];
    float EA[4] = {NEG, NEG, NEG, NEG}, EB[4] = {NEG, NEG, NEG, NEG};
    f4_t hc0, hc1, vc;               // carried h(r0-2), h(r0-1), v(r0-1)

// consume batch in buffer C (rows r0..r0+3 rel y0), emit rows r0-1..r0+2
#define CONSUME(C, EC, r0) do {                                   \
        f4_t hn0 = HM(C[0], EC[0]);                               \
        f4_t hn1 = HM(C[1], EC[1]);                               \
        f4_t hn2 = HM(C[2], EC[2]);                               \
        f4_t hn3 = HM(C[3], EC[3]);                               \
        EMIT((r0) - 1, vc,   hc0, hc1, hn0);                      \
        EMIT((r0),     C[0], hc1, hn0, hn1);                      \
        EMIT((r0) + 1, C[1], hn0, hn1, hn2);                      \
        EMIT((r0) + 2, C[2], hn1, hn2, hn3);                      \
        hc0 = hn2; hc1 = hn3; vc = C[3];                          \
    } while (0)

    // prologue: batch 0 (rows -1..2) + batch 1 (rows 3..6) in flight
    LD4(-1, A, EA);
    LD4( 3, B, EB);
    {
        f4_t h0 = HM(A[0], EA[0]);
        if (y0 == 0) h0 = NEG4;      // image top: row -1 doesn't exist
        f4_t h1 = HM(A[1], EA[1]);
        f4_t h2 = HM(A[2], EA[2]);
        f4_t h3 = HM(A[3], EA[3]);
        EMIT(0, A[1], h0, h1, h2);
        EMIT(1, A[2], h1, h2, h3);
        hc0 = h2; hc1 = h3; vc = A[3];
    }
    // steady state: issue next batch, consume current (always one in flight)
    LD4( 7, A, EA); CONSUME(B, EB,  3);   // m=1
    LD4(11, B, EB); CONSUME(A, EA,  7);   // m=2
    LD4(15, A, EA); CONSUME(B, EB, 11);   // m=3
    LD4(19, B, EB); CONSUME(A, EA, 15);   // m=4
    LD4(23, A, EA); CONSUME(B, EB, 19);   // m=5
    LD4(27, B, EB); CONSUME(A, EA, 23);   // m=6
    // epilogue: rows 31,32 (2 loads) in flight while consuming m=7
    f4_t EV0, EV1; float EE0 = NEG, EE1 = NEG;
    {
        int gy = y0 + 31;            // always <= 383
        EV0 = *(const f4_t*)(cb + (size_t)gy * WW);
        if (edge) EE0 = eb[(size_t)gy * WW];
        int gz = y0 + 32;
        gz = gz > HH - 1 ? HH - 1 : gz;
        EV1 = *(const f4_t*)(cb + (size_t)gz * WW);
        if (edge) EE1 = eb[(size_t)gz * WW];
    }
    CONSUME(B, EB, 27);                   // m=7: emits 26..29
    {
        f4_t hE0 = HM(EV0, EE0);
        f4_t hE1 = HM(EV1, EE1);
        if (ys == YS - 1) hE1 = NEG4;     // image bottom: row 32 doesn't exist
        EMIT(30, vc,  hc0, hc1, hE0);
        EMIT(31, EV0, hc1, hE0, hE1);
    }
#undef CONSUME
}

extern "C" void kernel_launch(void* const* d_in, const int* in_sizes, int n_in,
                              void* d_out, int out_size, void* d_ws, size_t ws_size,
                              hipStream_t stream) {
    const float* in = (const float*)d_in[0];
    float* out = (float*)d_out;
    heatmap_peaks_roll<<<NBLOCKS, 256, 0, stream>>>(in, out);
}